// Round 9
// baseline (99.969 us; speedup 1.0000x reference)
//
#include <hip/hip_runtime.h>
#include <stdint.h>

#define NI 128
#define NA 285
#define ND 183
#define NT 384
#define RAYS (NA * ND)        // 52155
#define PITCH 133             // dwords per packed row
#define PROWS 132
#define PLDS (PROWS * PITCH)  // 70,224 B
#define TPB 832               // 13 waves; grid 64 blocks/img
#define NTASK 828             // 92 j-values x 9 angle-chunks (32 angles each)
#define IDXMAX 17420          // 130*133+130: idx_mirror = IDXMAX - idx

typedef __fp16 half2v __attribute__((ext_vector_type(2)));

constexpr float PI_F  = 3.14159265358979323846f;
constexpr float RHO_F = 28.284271247461902f;   // 20*sqrt(2)
constexpr float DX_F  = 0.3125f;
constexpr float DT_F  = 2.0f * RHO_F / NT;

// Per-sample phase 1: clamp/floor/index + the 4 LDS dwords (primary pair +
// mirror pair). Separate from phase 2 so the 4-way group issues all 16 loads
// before any fdot2 consumes them. __launch_bounds__(TPB, 6) raises the VGPR
// budget to ~85 (LDS caps occupancy at 26 waves/CU = 6.5/SIMD anyway) so the
// compiler can actually keep 4 samples in flight (R8 allocated only 36 VGPRs
// and serialized the chains).
struct Smp { float a0, a1; unsigned int u0, u1, m0, m1; };

__device__ __forceinline__ Smp phase1(const unsigned int* P, float q0, float q1) {
    q0 = fminf(fmaxf(q0, 0.5f), 130.49f);   // v_med3; envelope-overrun -> ring
    q1 = fminf(fmaxf(q1, 0.5f), 130.49f);
    float f0 = floorf(q0);
    float f1 = floorf(q1);
    Smp s;
    s.a0 = q0 - f0;
    s.a1 = q1 - f1;
    int idx = (int)fmaf(f0, (float)PITCH, f1);   // exact (< 2^24)
    s.u0 = P[idx];
    s.u1 = P[idx + 1];
    s.m0 = P[IDXMAX - idx];
    s.m1 = P[IDXMAX - idx + 1];
    return s;
}

__device__ __forceinline__ void phase2(const Smp& s, float& accL, float& accR) {
    unsigned int wb = __builtin_bit_cast(unsigned int,
                          __builtin_amdgcn_cvt_pkrtz(1.0f - s.a0, s.a0));
    unsigned int wbm = __builtin_amdgcn_alignbit(wb, wb, 16);  // swap halves
    half2v w  = __builtin_bit_cast(half2v, wb);
    half2v wm = __builtin_bit_cast(half2v, wbm);
    float lL = __builtin_amdgcn_fdot2(__builtin_bit_cast(half2v, s.u0), w, 0.0f, false);
    float rL = __builtin_amdgcn_fdot2(__builtin_bit_cast(half2v, s.u1), w, 0.0f, false);
    float lR = __builtin_amdgcn_fdot2(__builtin_bit_cast(half2v, s.m0), wm, 0.0f, false);
    float rR = __builtin_amdgcn_fdot2(__builtin_bit_cast(half2v, s.m1), wm, 0.0f, false);
    accL += fmaf(s.a1, rL - lL, lL);
    accR += fmaf(s.a1, lR - rR, rR);   // == lR*a1 + rR*(1-a1)
}

// Mirror-paired + chord-split Radon with j-interleaved static schedule:
// wave w of block chunk owns task t = w*64 + chunk; j = t/9 spreads over the
// full detector range within every block -> per-block work equalized.
// Wave = 32 adjacent angles x 2 chord-halves at fixed j (tight envelope).
__global__ __launch_bounds__(TPB, 6) void radon_fwd(const float* __restrict__ x,
                                                    float* __restrict__ out) {
    __shared__ __align__(16) unsigned int P[PLDS];
    const int tid   = threadIdx.x;
    const int img   = blockIdx.x >> 6;
    const int chunk = blockIdx.x & 63;

    uint4* P4 = (uint4*)P;
    for (int i = tid; i < PLDS / 4; i += TPB) P4[i] = make_uint4(0, 0, 0, 0);
    __syncthreads();

    // Vertical-pair pack: P[pr*133+pc] = half2(pad[pr][pc], pad[pr+1][pc]),
    // pad = image with 2-cell zero ring (pad row/col = image index + 2).
    const float4* src = (const float4*)(x + img * NI * NI);
    for (int i = tid; i < 129 * 32; i += TPB) {
        int pr  = 1 + (i >> 5);
        int g   = i & 31;
        int rlo = pr - 2;
        int rhi = pr - 1;
        float4 vlo = (rlo >= 0)   ? src[rlo * 32 + g] : make_float4(0, 0, 0, 0);
        float4 vhi = (rhi <= 127) ? src[rhi * 32 + g] : make_float4(0, 0, 0, 0);
        int base = pr * PITCH + 2 + g * 4;
        P[base + 0] = __builtin_bit_cast(unsigned int, __builtin_amdgcn_cvt_pkrtz(vlo.x, vhi.x));
        P[base + 1] = __builtin_bit_cast(unsigned int, __builtin_amdgcn_cvt_pkrtz(vlo.y, vhi.y));
        P[base + 2] = __builtin_bit_cast(unsigned int, __builtin_amdgcn_cvt_pkrtz(vlo.z, vhi.z));
        P[base + 3] = __builtin_bit_cast(unsigned int, __builtin_amdgcn_cvt_pkrtz(vlo.w, vhi.w));
    }
    __syncthreads();

    const int w_id = tid >> 6;
    const int lane = tid & 63;
    const int t    = w_id * 64 + chunk;       // j-interleaved task id
    const int j    = t / 9;                   // detector pair index (0..91)
    const int c    = t - j * 9;               // angle chunk (0..8)
    const int a    = c * 32 + (lane >> 1);    // angle
    const int h    = lane & 1;                // chord half (0=down, 1=up)
    const bool valid = (t < NTASK) && (a < NA);

    const float ang = ((float)a + 0.5f) * (PI_F / (float)NA);
    float sn, cs;
    sincosf(ang, &sn, &cs);
    const float s   = -RHO_F + ((float)j + 0.5f) * (2.0f * RHO_F / (float)ND);
    const float t0v = -RHO_F + 0.5f * DT_F;
    const float inv_dx = 1.0f / DX_F;

    const float e0 = -s * sn;
    const float e1 =  s * cs;
    const float c0  = (e0 + t0v * cs + 20.0f) * inv_dx + 1.5f;
    const float c1  = (e1 + t0v * sn + 20.0f) * inv_dx + 1.5f;
    const float st0 = DT_F * cs * inv_dx;
    const float st1 = DT_F * sn * inv_dx;

    // Clip to bilinear support |p| <= 20 + DX/2 (+ fp margin).
    const float LIM = 20.157f;
    const float inv_cs = 1.0f / cs;
    const float inv_sn = 1.0f / sn;
    float ta = (-LIM - e0) * inv_cs, tb = (LIM - e0) * inv_cs;
    float tc = (-LIM - e1) * inv_sn, td = (LIM - e1) * inv_sn;
    float tlo = fmaxf(fminf(ta, tb), fminf(tc, td));
    float thi = fminf(fmaxf(ta, tb), fmaxf(tc, td));

    const float inv_dt = 1.0f / DT_F;
    float fk0 = fminf(fmaxf(ceilf((tlo - t0v) * inv_dt), 0.0f), 384.0f);
    float fk1 = fminf(fmaxf(floorf((thi - t0v) * inv_dt), -1.0f), 383.0f);
    const int kmin = (int)fk0;
    const int kmax = (int)fk1;
    const int kmid = (kmin + kmax + 1) >> 1;

    int mylen = h ? (kmax - kmid + 1) : (kmid - kmin);
    if (mylen < 0 || !valid) mylen = 0;

    // Wave envelope (lanes = adjacent angles at fixed j -> tight).
    int Lw = mylen;
    #pragma unroll
    for (int off = 32; off >= 1; off >>= 1)
        Lw = max(Lw, __shfl_xor(Lw, off, 64));

    const float sgn  = h ? 1.0f : -1.0f;
    const float st0h = st0 * sgn;
    const float st1h = st1 * sgn;
    const float ks   = (float)(h ? kmid : kmid - 1);

    // 4 independent in-flight sample coordinates (walk outward from chord
    // middle; over-run samples clamp into the zero ring -> contribute 0).
    float i0a = fmaf(ks, st0, c0);
    float i1a = fmaf(ks, st1, c1);
    float i0b = i0a + st0h, i1b = i1a + st1h;
    float i0c = i0b + st0h, i1c = i1b + st1h;
    float i0d = i0c + st0h, i1d = i1c + st1h;
    const float j0 = 4.0f * st0h;
    const float j1 = 4.0f * st1h;
    float accL0 = 0.0f, accR0 = 0.0f, accL1 = 0.0f, accR1 = 0.0f;

    #pragma unroll 1
    for (int m = 0; m < Lw; m += 4) {
        Smp sa = phase1(P, i0a, i1a);
        Smp sb = phase1(P, i0b, i1b);
        Smp sc = phase1(P, i0c, i1c);
        Smp sd = phase1(P, i0d, i1d);
        i0a += j0; i1a += j1;
        i0b += j0; i1b += j1;
        i0c += j0; i1c += j1;
        i0d += j0; i1d += j1;
        phase2(sa, accL0, accR0);
        phase2(sb, accL1, accR1);
        phase2(sc, accL0, accR0);
        phase2(sd, accL1, accR1);
    }
    float accL = accL0 + accL1;
    float accR = accR0 + accR1;

    // Combine the two chord halves (adjacent lanes share a, differ in h).
    accL += __shfl_xor(accL, 1, 64);
    accR += __shfl_xor(accR, 1, 64);

    if (valid) {
        const float sc = DT_F / 12.0f;
        const int base = img * RAYS + a * ND;
        int det = h ? (182 - j) : j;
        float v = h ? accR : accL;
        out[base + det] = v * sc;
    }
}

extern "C" void kernel_launch(void* const* d_in, const int* in_sizes, int n_in,
                              void* d_out, int out_size, void* d_ws, size_t ws_size,
                              hipStream_t stream) {
    const float* x = (const float*)d_in[0];
    float* out = (float*)d_out;
    const int B = in_sizes[0] / (NI * NI);   // 8
    dim3 grid(B * 64);
    radon_fwd<<<grid, TPB, 0, stream>>>(x, out);
}

// Round 12
// 86.299 us; speedup vs baseline: 1.1584x; 1.1584x over previous
//
#include <hip/hip_runtime.h>
#include <stdint.h>

#define NI 128
#define NA 285
#define ND 183
#define NT 384
#define RAYS (NA * ND)        // 52155
#define PITCH 133             // dwords per packed row
#define PROWS 132
#define PLDS (PROWS * PITCH)  // 70,224 B -> 2 blocks/CU
#define TPB 832               // 13 waves; grid 64 blocks/img
#define NTASK 828             // 92 j-values x 9 angle-chunks (16 angle-pairs)
#define IDXM 17420            // 130*133+130: det-mirror idx' = IDXM - idx

typedef __fp16 half2v __attribute__((ext_vector_type(2)));

constexpr float PI_F  = 3.14159265358979323846f;
constexpr float RHO_F = 28.284271247461902f;   // 20*sqrt(2)
constexpr float DX_F  = 0.3125f;
constexpr float DT_F  = 2.0f * RHO_F / NT;

// 4-ray symmetry-group Radon. Each lane walks ONE quarter-chord of ray
// (ap, j) and accumulates FOUR rays sharing the sample geometry:
//   R0=(ap,j): idx            R1=(ap,182-j):    IDXM-idx   (proven R5-R9)
//   R2=(284-ap,j): idx+130-2*f1 (col flip)  R3=(284-ap,182-j): IDXM-idx2
// (ang'=pi-ang => sn'=sn, cs'=-cs; t-grid symmetric under t->-t, so R2/R3
// samples are R0's with col/row flipped, summed in reverse order — sums
// equal.) Vertical fp16-pair LDS (P[r][c]=half2(pad[r][c],pad[r+1][c])),
// weights via 2 pk products wA=w*(1-a1), wB=w*a1 + half-swaps (alignbit).
// Exact per-lane quarter lengths (divergent loop) — no clamps, no overrun.
__global__ __launch_bounds__(TPB) void radon_fwd(const float* __restrict__ x,
                                                 float* __restrict__ out) {
    __shared__ __align__(16) unsigned int P[PLDS];
    const int tid   = threadIdx.x;
    const int img   = blockIdx.x >> 6;
    const int chunk = blockIdx.x & 63;

    uint4* P4 = (uint4*)P;
    for (int i = tid; i < PLDS / 4; i += TPB) P4[i] = make_uint4(0, 0, 0, 0);
    __syncthreads();

    // Vertical-pair pack: P[pr*133+pc] = half2(pad[pr][pc], pad[pr+1][pc]),
    // pad = image with 2-cell zero ring (pad row/col = image index + 2).
    const float4* src = (const float4*)(x + img * NI * NI);
    for (int i = tid; i < 129 * 32; i += TPB) {
        int pr  = 1 + (i >> 5);
        int g   = i & 31;
        int rlo = pr - 2;
        int rhi = pr - 1;
        float4 vlo = (rlo >= 0)   ? src[rlo * 32 + g] : make_float4(0, 0, 0, 0);
        float4 vhi = (rhi <= 127) ? src[rhi * 32 + g] : make_float4(0, 0, 0, 0);
        int base = pr * PITCH + 2 + g * 4;
        P[base + 0] = __builtin_bit_cast(unsigned int, __builtin_amdgcn_cvt_pkrtz(vlo.x, vhi.x));
        P[base + 1] = __builtin_bit_cast(unsigned int, __builtin_amdgcn_cvt_pkrtz(vlo.y, vhi.y));
        P[base + 2] = __builtin_bit_cast(unsigned int, __builtin_amdgcn_cvt_pkrtz(vlo.z, vhi.z));
        P[base + 3] = __builtin_bit_cast(unsigned int, __builtin_amdgcn_cvt_pkrtz(vlo.w, vhi.w));
    }
    __syncthreads();

    const int w_id = tid >> 6;
    const int lane = tid & 63;
    const int t    = w_id * 64 + chunk;       // j-interleaved task id
    const int j    = t / 9;                   // detector pair index (0..91)
    const int apc  = t - j * 9;               // angle-pair chunk (0..8)
    const int ap   = apc * 16 + (lane >> 2);  // angle 0..142 valid (143=pad)
    const int q    = lane & 3;                // chord quarter
    const bool valid = (t < NTASK) && (ap < 143);

    const float ang = ((float)ap + 0.5f) * (PI_F / (float)NA);
    float sn, cs;
    sincosf(ang, &sn, &cs);
    const float s   = -RHO_F + ((float)j + 0.5f) * (2.0f * RHO_F / (float)ND);
    const float t0v = -RHO_F + 0.5f * DT_F;
    const float inv_dx = 1.0f / DX_F;

    const float e0 = -s * sn;
    const float e1 =  s * cs;
    const float c0p = (e0 + t0v * cs + 20.0f) * inv_dx + 1.5f;  // padded
    const float c1p = (e1 + t0v * sn + 20.0f) * inv_dx + 1.5f;
    const float st0 = DT_F * cs * inv_dx;
    const float st1 = DT_F * sn * inv_dx;

    // Clip to bilinear support |p| <= 20 + DX/2 (+ fp margin).
    const float LIM = 20.157f;
    const float inv_cs = 1.0f / cs;
    const float inv_sn = 1.0f / sn;
    float ta = (-LIM - e0) * inv_cs, tb = (LIM - e0) * inv_cs;
    float tc = (-LIM - e1) * inv_sn, td = (LIM - e1) * inv_sn;
    float tlo = fmaxf(fminf(ta, tb), fminf(tc, td));
    float thi = fminf(fmaxf(ta, tb), fmaxf(tc, td));

    const float inv_dt = 1.0f / DT_F;
    float fk0 = fminf(fmaxf(ceilf((tlo - t0v) * inv_dt), 0.0f), 384.0f);
    float fk1 = fminf(fmaxf(floorf((thi - t0v) * inv_dt), -1.0f), 383.0f);
    const int kmin = (int)fk0;
    const int kmax = (int)fk1;
    const int kmid = (kmin + kmax + 1) >> 1;
    const int kql  = (kmin + kmid) >> 1;
    const int kqu  = (kmid + kmax + 1) >> 1;

    // Quarter q: q0=[kql,kmid) down from kmid-1; q1=[kmin,kql) down from
    // kql-1; q2=[kmid,kqu) up from kmid; q3=[kqu,kmax] up from kqu.
    int l0 = kmid - kql, l1 = kql - kmin, l2 = kqu - kmid, l3 = kmax - kqu + 1;
    int len = (q & 2) ? ((q & 1) ? l3 : l2) : ((q & 1) ? l1 : l0);
    int ks  = (q & 2) ? ((q & 1) ? kqu : kmid) : ((q & 1) ? (kql - 1) : (kmid - 1));
    if (!valid) len = 0;
    len = max(len, 0);
    const float sgn  = (q & 2) ? 1.0f : -1.0f;
    const float st0s = st0 * sgn;
    const float st1s = st1 * sgn;
    float i0 = fmaf((float)ks, st0, c0p);
    float i1 = fmaf((float)ks, st1, c1p);

    float acc0 = 0.0f, acc1 = 0.0f, acc2 = 0.0f, acc3 = 0.0f;

    #pragma unroll 2
    for (int m = 0; m < len; ++m) {
        float f0 = floorf(i0);
        float f1 = floorf(i1);
        float a0 = i0 - f0;
        float a1 = i1 - f1;
        int f1i = (int)f1;
        int idx = (int)fmaf(f0, 133.0f, f1);
        i0 += st0s;
        i1 += st1s;
        int idx1 = IDXM - idx;
        int idx2 = (idx + 130) - (f1i << 1);
        int idx3 = IDXM - idx2;
        unsigned int u0 = P[idx],  u1 = P[idx + 1];
        unsigned int m0 = P[idx1], m1 = P[idx1 + 1];
        unsigned int r0 = P[idx2], r1 = P[idx2 + 1];
        unsigned int s0 = P[idx3], s1 = P[idx3 + 1];
        half2v w  = __builtin_amdgcn_cvt_pkrtz(1.0f - a0, a0);
        half2v hA = __builtin_amdgcn_cvt_pkrtz(1.0f - a1, 1.0f - a1);
        half2v hB = __builtin_amdgcn_cvt_pkrtz(a1, a1);
        half2v wA = w * hA;                       // v_pk_mul_f16
        half2v wB = w * hB;
        unsigned int wAu = __builtin_bit_cast(unsigned int, wA);
        unsigned int wBu = __builtin_bit_cast(unsigned int, wB);
        half2v wmA = __builtin_bit_cast(half2v, __builtin_amdgcn_alignbit(wAu, wAu, 16));
        half2v wmB = __builtin_bit_cast(half2v, __builtin_amdgcn_alignbit(wBu, wBu, 16));
        acc0 = __builtin_amdgcn_fdot2(__builtin_bit_cast(half2v, u0), wA, acc0, false);
        acc0 = __builtin_amdgcn_fdot2(__builtin_bit_cast(half2v, u1), wB, acc0, false);
        acc1 = __builtin_amdgcn_fdot2(__builtin_bit_cast(half2v, m0), wmB, acc1, false);
        acc1 = __builtin_amdgcn_fdot2(__builtin_bit_cast(half2v, m1), wmA, acc1, false);
        acc2 = __builtin_amdgcn_fdot2(__builtin_bit_cast(half2v, r0), wB, acc2, false);
        acc2 = __builtin_amdgcn_fdot2(__builtin_bit_cast(half2v, r1), wA, acc2, false);
        acc3 = __builtin_amdgcn_fdot2(__builtin_bit_cast(half2v, s0), wmA, acc3, false);
        acc3 = __builtin_amdgcn_fdot2(__builtin_bit_cast(half2v, s1), wmB, acc3, false);
    }

    // Combine quarters: butterfly over the 4-lane group (same j, ap).
    acc0 += __shfl_xor(acc0, 1, 64); acc0 += __shfl_xor(acc0, 2, 64);
    acc1 += __shfl_xor(acc1, 1, 64); acc1 += __shfl_xor(acc1, 2, 64);
    acc2 += __shfl_xor(acc2, 1, 64); acc2 += __shfl_xor(acc2, 2, 64);
    acc3 += __shfl_xor(acc3, 1, 64); acc3 += __shfl_xor(acc3, 2, 64);

    if (valid) {
        float v = (q == 0) ? acc0 : (q == 1) ? acc1 : (q == 2) ? acc2 : acc3;
        int ao  = (q & 2) ? (284 - ap) : ap;
        int det = (q & 1) ? (182 - j) : j;
        // ap==142 self-pairs (284-142==142): q2/q3 rewrite q0/q1's outputs
        // with fp-equivalent values — benign.
        out[img * RAYS + ao * ND + det] = v * (DT_F / 12.0f);
    }
}

extern "C" void kernel_launch(void* const* d_in, const int* in_sizes, int n_in,
                              void* d_out, int out_size, void* d_ws, size_t ws_size,
                              hipStream_t stream) {
    const float* x = (const float*)d_in[0];
    float* out = (float*)d_out;
    const int B = in_sizes[0] / (NI * NI);   // 8
    dim3 grid(B * 64);
    radon_fwd<<<grid, TPB, 0, stream>>>(x, out);
}

// Round 14
// 84.481 us; speedup vs baseline: 1.1833x; 1.0215x over previous
//
#include <hip/hip_runtime.h>
#include <stdint.h>

#define NI 128
#define NA 285
#define ND 183
#define NT 384
#define RAYS (NA * ND)        // 52155
#define PITCH 133             // dwords per packed row
#define PROWS 132
#define PLDS (PROWS * PITCH + 1)  // 17557 dwords = 70,228 B -> 2 blocks/CU
#define TPB 832               // 13 waves; grid 64 blocks/img
#define NTASK 828             // 92 j-values x 9 angle-pair chunks
#define IDXM 17420            // 130*133+130: det-mirror idx' = IDXM - idx

typedef __fp16 half2v __attribute__((ext_vector_type(2)));

constexpr float PI_F  = 3.14159265358979323846f;
constexpr float RHO_F = 28.284271247461902f;   // 20*sqrt(2)
constexpr float DX_F  = 0.3125f;
constexpr float DT_F  = 2.0f * RHO_F / NT;

// 4-ray symmetry-group Radon (R12 math) with UNIFORM control flow:
// lane group q = (h,p): h = walk direction (0 = down from kmid-1, 1 = up
// from kmid), p = parity (stride 2). All overrun exits the support square
// outward -> med3 clamp lands every one of the 4 symmetric reads on zero
// rows/cols (pad rows/cols {0,1,130,131} are zero). NOTE: column 1 MUST
// stay zero (pad col 1 = image col -1) — mirror reads at col' = 130-f1 hit
// it for in-support boundary samples (R13's col-1 strip was the bug).
__global__ __launch_bounds__(TPB) void radon_fwd(const float* __restrict__ x,
                                                 float* __restrict__ out) {
    __shared__ __align__(16) unsigned int P[PLDS];
    const int tid   = threadIdx.x;
    const int img   = blockIdx.x >> 6;
    const int chunk = blockIdx.x & 63;

    // Ring-only zero fill (disjoint from pack writes -> single barrier).
    // rows 0,130,131 full; rows 1..129 cols {0,1,130,131,132}.
    for (int i = tid; i < 1432; i += TPB) {
        int r, c;
        if (i < 399) { r = (i < 133) ? 0 : (i < 266 ? 130 : 131);
                       c = i - ((i < 133) ? 0 : (i < 266 ? 133 : 266)); }
        else { int k = i - 399; r = 1 + (k >> 3);
               const int map[8] = {0, 1, 130, 131, 132, 0, 1, 130};
               c = map[k & 7]; }
        P[r * PITCH + c] = 0;
    }
    if (tid == 0) P[PLDS - 1] = 0;

    // Vertical-pair pack: P[pr*133+pc] = half2(pad[pr][pc], pad[pr+1][pc]),
    // pad = image with 2-cell zero ring (pad row/col = image index + 2).
    // Only pc in [2,129] is ever nonzero; all other columns stay zero.
    const float4* src = (const float4*)(x + img * NI * NI);
    for (int i = tid; i < 129 * 32; i += TPB) {
        int pr  = 1 + (i >> 5);
        int g   = i & 31;
        int rlo = pr - 2;
        int rhi = pr - 1;
        float4 vlo = (rlo >= 0)   ? src[rlo * 32 + g] : make_float4(0, 0, 0, 0);
        float4 vhi = (rhi <= 127) ? src[rhi * 32 + g] : make_float4(0, 0, 0, 0);
        int base = pr * PITCH + 2 + g * 4;
        P[base + 0] = __builtin_bit_cast(unsigned int, __builtin_amdgcn_cvt_pkrtz(vlo.x, vhi.x));
        P[base + 1] = __builtin_bit_cast(unsigned int, __builtin_amdgcn_cvt_pkrtz(vlo.y, vhi.y));
        P[base + 2] = __builtin_bit_cast(unsigned int, __builtin_amdgcn_cvt_pkrtz(vlo.z, vhi.z));
        P[base + 3] = __builtin_bit_cast(unsigned int, __builtin_amdgcn_cvt_pkrtz(vlo.w, vhi.w));
    }
    __syncthreads();

    const int w_id = tid >> 6;
    const int lane = tid & 63;
    const int t    = w_id * 64 + chunk;       // j-interleaved task id
    const int j    = t / 9;                   // detector pair index (0..91)
    const int apc  = t - j * 9;               // angle-pair chunk (0..8)
    const int ap   = apc * 16 + (lane >> 2);  // angle 0..142 valid (143=pad)
    const int q    = lane & 3;                // (h,p): h=q>>1, p=q&1
    const bool valid = (t < NTASK) && (ap < 143);

    const float ang = ((float)ap + 0.5f) * (PI_F / (float)NA);
    float sn, cs;
    sincosf(ang, &sn, &cs);
    const float s   = -RHO_F + ((float)j + 0.5f) * (2.0f * RHO_F / (float)ND);
    const float t0v = -RHO_F + 0.5f * DT_F;
    const float inv_dx = 1.0f / DX_F;

    const float e0 = -s * sn;
    const float e1 =  s * cs;
    const float c0p = (e0 + t0v * cs + 20.0f) * inv_dx + 1.5f;  // padded
    const float c1p = (e1 + t0v * sn + 20.0f) * inv_dx + 1.5f;
    const float st0 = DT_F * cs * inv_dx;
    const float st1 = DT_F * sn * inv_dx;

    // Clip to bilinear support |p| <= 20 + DX/2 (+ fp margin).
    const float LIM = 20.157f;
    const float inv_cs = 1.0f / cs;
    const float inv_sn = 1.0f / sn;
    float ta = (-LIM - e0) * inv_cs, tb = (LIM - e0) * inv_cs;
    float tc = (-LIM - e1) * inv_sn, td = (LIM - e1) * inv_sn;
    float tlo = fmaxf(fminf(ta, tb), fminf(tc, td));
    float thi = fminf(fmaxf(ta, tb), fmaxf(tc, td));

    const float inv_dt = 1.0f / DT_F;
    float fk0 = fminf(fmaxf(ceilf((tlo - t0v) * inv_dt), 0.0f), 384.0f);
    float fk1 = fminf(fmaxf(floorf((thi - t0v) * inv_dt), -1.0f), 383.0f);
    const int kmin = (int)fk0;
    const int kmax = (int)fk1;
    const int kmid = (kmin + kmax + 1) >> 1;

    // Half lengths; lane runs ceil(max/2) steps at stride 2 (parity split).
    int ldown = kmid - kmin;
    int lup   = kmax - kmid + 1;
    int mylen = (max(max(ldown, lup), 0) + 1) >> 1;
    if (!valid) mylen = 0;

    // Wave envelope (16 adjacent angle-pairs at fixed j -> tight).
    int Lw = mylen;
    #pragma unroll
    for (int off = 32; off >= 1; off >>= 1)
        Lw = max(Lw, __shfl_xor(Lw, off, 64));

    const int h = q >> 1;
    const int p = q & 1;
    const float sgn  = h ? 1.0f : -1.0f;
    const float st0s = st0 * (2.0f * sgn);
    const float st1s = st1 * (2.0f * sgn);
    const int   ks   = h ? (kmid + p) : (kmid - 1 - p);
    float i0 = fmaf((float)ks, st0, c0p);
    float i1 = fmaf((float)ks, st1, c1p);

    float acc0 = 0.0f, acc1 = 0.0f, acc2 = 0.0f, acc3 = 0.0f;

    #pragma unroll 4
    for (int m = 0; m < Lw; ++m) {
        // Clamp [0.5,130.49]: identity in-support; overrun -> zero rows/cols
        // for all 4 symmetric reads (idx,idx1,idx2,idx3 within [0,17421]).
        float q0 = fminf(fmaxf(i0, 0.5f), 130.49f);
        float q1 = fminf(fmaxf(i1, 0.5f), 130.49f);
        i0 += st0s;
        i1 += st1s;
        float f0 = floorf(q0);
        float f1 = floorf(q1);
        float a0 = q0 - f0;
        float a1 = q1 - f1;
        int f1i = (int)f1;
        int idx = (int)fmaf(f0, 133.0f, f1);
        int idx1 = IDXM - idx;
        int idx2 = (idx + 130) - (f1i << 1);
        int idx3 = IDXM - idx2;
        unsigned int u0 = P[idx],  u1 = P[idx + 1];
        unsigned int m0 = P[idx1], m1 = P[idx1 + 1];
        unsigned int r0 = P[idx2], r1 = P[idx2 + 1];
        unsigned int s0 = P[idx3], s1 = P[idx3 + 1];
        half2v w  = __builtin_amdgcn_cvt_pkrtz(1.0f - a0, a0);
        half2v hA = __builtin_amdgcn_cvt_pkrtz(1.0f - a1, 1.0f - a1);
        half2v hB = __builtin_amdgcn_cvt_pkrtz(a1, a1);
        half2v wA = w * hA;                       // v_pk_mul_f16
        half2v wB = w * hB;
        unsigned int wAu = __builtin_bit_cast(unsigned int, wA);
        unsigned int wBu = __builtin_bit_cast(unsigned int, wB);
        half2v wmA = __builtin_bit_cast(half2v, __builtin_amdgcn_alignbit(wAu, wAu, 16));
        half2v wmB = __builtin_bit_cast(half2v, __builtin_amdgcn_alignbit(wBu, wBu, 16));
        acc0 = __builtin_amdgcn_fdot2(__builtin_bit_cast(half2v, u0), wA, acc0, false);
        acc0 = __builtin_amdgcn_fdot2(__builtin_bit_cast(half2v, u1), wB, acc0, false);
        acc1 = __builtin_amdgcn_fdot2(__builtin_bit_cast(half2v, m0), wmB, acc1, false);
        acc1 = __builtin_amdgcn_fdot2(__builtin_bit_cast(half2v, m1), wmA, acc1, false);
        acc2 = __builtin_amdgcn_fdot2(__builtin_bit_cast(half2v, r0), wB, acc2, false);
        acc2 = __builtin_amdgcn_fdot2(__builtin_bit_cast(half2v, r1), wA, acc2, false);
        acc3 = __builtin_amdgcn_fdot2(__builtin_bit_cast(half2v, s0), wmA, acc3, false);
        acc3 = __builtin_amdgcn_fdot2(__builtin_bit_cast(half2v, s1), wmB, acc3, false);
    }

    // Combine the 4-lane group (same j, ap; different h,p subsets).
    acc0 += __shfl_xor(acc0, 1, 64); acc0 += __shfl_xor(acc0, 2, 64);
    acc1 += __shfl_xor(acc1, 1, 64); acc1 += __shfl_xor(acc1, 2, 64);
    acc2 += __shfl_xor(acc2, 1, 64); acc2 += __shfl_xor(acc2, 2, 64);
    acc3 += __shfl_xor(acc3, 1, 64); acc3 += __shfl_xor(acc3, 2, 64);

    if (valid) {
        float v = (q == 0) ? acc0 : (q == 1) ? acc1 : (q == 2) ? acc2 : acc3;
        int ao  = (q & 2) ? (284 - ap) : ap;
        int det = (q & 1) ? (182 - j) : j;
        // ap==142 self-pairs: q2/q3 rewrite q0/q1's outputs with fp-equal
        // values — benign.
        out[img * RAYS + ao * ND + det] = v * (DT_F / 12.0f);
    }
}

extern "C" void kernel_launch(void* const* d_in, const int* in_sizes, int n_in,
                              void* d_out, int out_size, void* d_ws, size_t ws_size,
                              hipStream_t stream) {
    const float* x = (const float*)d_in[0];
    float* out = (float*)d_out;
    const int B = in_sizes[0] / (NI * NI);   // 8
    dim3 grid(B * 64);
    radon_fwd<<<grid, TPB, 0, stream>>>(x, out);
}

// Round 15
// 82.681 us; speedup vs baseline: 1.2091x; 1.0218x over previous
//
#include <hip/hip_runtime.h>
#include <stdint.h>

#define NI 128
#define NA 285
#define ND 183
#define NT 384
#define RAYS (NA * ND)        // 52155
#define PITCH 133             // dwords per packed row
#define PROWS 132
#define PLDS (PROWS * PITCH + 1)  // 17557 dwords = 70,228 B -> 2 blocks/CU
#define TPB 832               // 13 waves; grid 64 blocks/img
#define NTASK 828             // 92 j-values x 9 angle-pair chunks
#define IDXM 17420            // 130*133+130: det-mirror idx' = IDXM - idx
#define BIDXM (IDXM * 4)      // byte-domain mirror constant

typedef __fp16 half2v __attribute__((ext_vector_type(2)));

constexpr float PI_F  = 3.14159265358979323846f;
constexpr float RHO_F = 28.284271247461902f;   // 20*sqrt(2)
constexpr float DX_F  = 0.3125f;
constexpr float DT_F  = 2.0f * RHO_F / NT;

// 4-ray symmetry-group Radon, uniform control flow (R14) + R15 micro-opts:
// (a) all four LDS byte offsets computed in float (f1b=4*f1; bidx =
//     cvt(fma(f0,532,f1b)); bidx2 = cvt(fma(f0,532,520-f1b)); mirrors by
//     constant-minus) — kills the int shl/add chain; exact (< 2^24).
// (b) wA = w - w*a1 instead of w*(1-a1) — one pk_sub replaces sub+pkrtz.
// Column 1 MUST stay zero (pad col 1 = image col -1): mirror reads at
// col' = 130-f1 hit it for in-support boundary samples (R13's bug).
__global__ __launch_bounds__(TPB) void radon_fwd(const float* __restrict__ x,
                                                 float* __restrict__ out) {
    __shared__ __align__(16) unsigned int P[PLDS];
    const int tid   = threadIdx.x;
    const int img   = blockIdx.x >> 6;
    const int chunk = blockIdx.x & 63;

    // Ring-only zero fill (disjoint from pack writes -> single barrier).
    // rows 0,130,131 full; rows 1..129 cols {0,1,130,131,132}.
    for (int i = tid; i < 1432; i += TPB) {
        int r, c;
        if (i < 399) { r = (i < 133) ? 0 : (i < 266 ? 130 : 131);
                       c = i - ((i < 133) ? 0 : (i < 266 ? 133 : 266)); }
        else { int k = i - 399; r = 1 + (k >> 3);
               const int map[8] = {0, 1, 130, 131, 132, 0, 1, 130};
               c = map[k & 7]; }
        P[r * PITCH + c] = 0;
    }
    if (tid == 0) P[PLDS - 1] = 0;

    // Vertical-pair pack: P[pr*133+pc] = half2(pad[pr][pc], pad[pr+1][pc]),
    // pad = image with 2-cell zero ring. Only pc in [2,129] nonzero.
    const float4* src = (const float4*)(x + img * NI * NI);
    for (int i = tid; i < 129 * 32; i += TPB) {
        int pr  = 1 + (i >> 5);
        int g   = i & 31;
        int rlo = pr - 2;
        int rhi = pr - 1;
        float4 vlo = (rlo >= 0)   ? src[rlo * 32 + g] : make_float4(0, 0, 0, 0);
        float4 vhi = (rhi <= 127) ? src[rhi * 32 + g] : make_float4(0, 0, 0, 0);
        int base = pr * PITCH + 2 + g * 4;
        P[base + 0] = __builtin_bit_cast(unsigned int, __builtin_amdgcn_cvt_pkrtz(vlo.x, vhi.x));
        P[base + 1] = __builtin_bit_cast(unsigned int, __builtin_amdgcn_cvt_pkrtz(vlo.y, vhi.y));
        P[base + 2] = __builtin_bit_cast(unsigned int, __builtin_amdgcn_cvt_pkrtz(vlo.z, vhi.z));
        P[base + 3] = __builtin_bit_cast(unsigned int, __builtin_amdgcn_cvt_pkrtz(vlo.w, vhi.w));
    }
    __syncthreads();

    const int w_id = tid >> 6;
    const int lane = tid & 63;
    const int t    = w_id * 64 + chunk;       // j-interleaved task id
    const int j    = t / 9;                   // detector pair index (0..91)
    const int apc  = t - j * 9;               // angle-pair chunk (0..8)
    const int ap   = apc * 16 + (lane >> 2);  // angle 0..142 valid (143=pad)
    const int q    = lane & 3;                // (h,p): h=q>>1, p=q&1
    const bool valid = (t < NTASK) && (ap < 143);

    const float ang = ((float)ap + 0.5f) * (PI_F / (float)NA);
    float sn, cs;
    sincosf(ang, &sn, &cs);
    const float s   = -RHO_F + ((float)j + 0.5f) * (2.0f * RHO_F / (float)ND);
    const float t0v = -RHO_F + 0.5f * DT_F;
    const float inv_dx = 1.0f / DX_F;

    const float e0 = -s * sn;
    const float e1 =  s * cs;
    const float c0p = (e0 + t0v * cs + 20.0f) * inv_dx + 1.5f;  // padded
    const float c1p = (e1 + t0v * sn + 20.0f) * inv_dx + 1.5f;
    const float st0 = DT_F * cs * inv_dx;
    const float st1 = DT_F * sn * inv_dx;

    // Clip to bilinear support |p| <= 20 + DX/2 (+ fp margin).
    const float LIM = 20.157f;
    const float inv_cs = 1.0f / cs;
    const float inv_sn = 1.0f / sn;
    float ta = (-LIM - e0) * inv_cs, tb = (LIM - e0) * inv_cs;
    float tc = (-LIM - e1) * inv_sn, td = (LIM - e1) * inv_sn;
    float tlo = fmaxf(fminf(ta, tb), fminf(tc, td));
    float thi = fminf(fmaxf(ta, tb), fmaxf(tc, td));

    const float inv_dt = 1.0f / DT_F;
    float fk0 = fminf(fmaxf(ceilf((tlo - t0v) * inv_dt), 0.0f), 384.0f);
    float fk1 = fminf(fmaxf(floorf((thi - t0v) * inv_dt), -1.0f), 383.0f);
    const int kmin = (int)fk0;
    const int kmax = (int)fk1;
    const int kmid = (kmin + kmax + 1) >> 1;

    // Half lengths; lane runs ceil(max/2) steps at stride 2 (parity split).
    int ldown = kmid - kmin;
    int lup   = kmax - kmid + 1;
    int mylen = (max(max(ldown, lup), 0) + 1) >> 1;
    if (!valid) mylen = 0;

    // Wave envelope (16 adjacent angle-pairs at fixed j -> tight).
    int Lw = mylen;
    #pragma unroll
    for (int off = 32; off >= 1; off >>= 1)
        Lw = max(Lw, __shfl_xor(Lw, off, 64));

    const int h = q >> 1;
    const int p = q & 1;
    const float sgn  = h ? 1.0f : -1.0f;
    const float st0s = st0 * (2.0f * sgn);
    const float st1s = st1 * (2.0f * sgn);
    const int   ks   = h ? (kmid + p) : (kmid - 1 - p);
    float i0 = fmaf((float)ks, st0, c0p);
    float i1 = fmaf((float)ks, st1, c1p);

    const char* Pb = (const char*)P;
    float acc0 = 0.0f, acc1 = 0.0f, acc2 = 0.0f, acc3 = 0.0f;

    #pragma unroll 4
    for (int m = 0; m < Lw; ++m) {
        // Clamp [0.5,130.49]: identity in-support; overrun -> zero rows/cols
        // for all 4 symmetric reads.
        float q0 = fminf(fmaxf(i0, 0.5f), 130.49f);
        float q1 = fminf(fmaxf(i1, 0.5f), 130.49f);
        i0 += st0s;
        i1 += st1s;
        float f0 = floorf(q0);
        float f1 = floorf(q1);
        float a0 = q0 - f0;
        float a1 = q1 - f1;
        // Byte offsets, float-domain (exact: max 130*532+520 = 69680 < 2^24).
        float f1b = 4.0f * f1;
        int bidx  = (int)fmaf(f0, 532.0f, f1b);
        int bidx1 = BIDXM - bidx;
        int bidx2 = (int)fmaf(f0, 532.0f, 520.0f - f1b);
        int bidx3 = BIDXM - bidx2;
        unsigned int u0 = *(const unsigned int*)(Pb + bidx);
        unsigned int u1 = *(const unsigned int*)(Pb + bidx + 4);
        unsigned int m0 = *(const unsigned int*)(Pb + bidx1);
        unsigned int m1 = *(const unsigned int*)(Pb + bidx1 + 4);
        unsigned int r0 = *(const unsigned int*)(Pb + bidx2);
        unsigned int r1 = *(const unsigned int*)(Pb + bidx2 + 4);
        unsigned int s0 = *(const unsigned int*)(Pb + bidx3);
        unsigned int s1 = *(const unsigned int*)(Pb + bidx3 + 4);
        half2v w  = __builtin_amdgcn_cvt_pkrtz(1.0f - a0, a0);
        half2v b1 = __builtin_amdgcn_cvt_pkrtz(a1, a1);
        half2v wB = w * b1;                       // v_pk_mul_f16
        half2v wA = w - wB;                       // v_pk_add_f16 (== w*(1-a1))
        unsigned int wAu = __builtin_bit_cast(unsigned int, wA);
        unsigned int wBu = __builtin_bit_cast(unsigned int, wB);
        half2v wmA = __builtin_bit_cast(half2v, __builtin_amdgcn_alignbit(wAu, wAu, 16));
        half2v wmB = __builtin_bit_cast(half2v, __builtin_amdgcn_alignbit(wBu, wBu, 16));
        acc0 = __builtin_amdgcn_fdot2(__builtin_bit_cast(half2v, u0), wA, acc0, false);
        acc0 = __builtin_amdgcn_fdot2(__builtin_bit_cast(half2v, u1), wB, acc0, false);
        acc1 = __builtin_amdgcn_fdot2(__builtin_bit_cast(half2v, m0), wmB, acc1, false);
        acc1 = __builtin_amdgcn_fdot2(__builtin_bit_cast(half2v, m1), wmA, acc1, false);
        acc2 = __builtin_amdgcn_fdot2(__builtin_bit_cast(half2v, r0), wB, acc2, false);
        acc2 = __builtin_amdgcn_fdot2(__builtin_bit_cast(half2v, r1), wA, acc2, false);
        acc3 = __builtin_amdgcn_fdot2(__builtin_bit_cast(half2v, s0), wmA, acc3, false);
        acc3 = __builtin_amdgcn_fdot2(__builtin_bit_cast(half2v, s1), wmB, acc3, false);
    }

    // Combine the 4-lane group (same j, ap; different h,p subsets).
    acc0 += __shfl_xor(acc0, 1, 64); acc0 += __shfl_xor(acc0, 2, 64);
    acc1 += __shfl_xor(acc1, 1, 64); acc1 += __shfl_xor(acc1, 2, 64);
    acc2 += __shfl_xor(acc2, 1, 64); acc2 += __shfl_xor(acc2, 2, 64);
    acc3 += __shfl_xor(acc3, 1, 64); acc3 += __shfl_xor(acc3, 2, 64);

    if (valid) {
        float v = (q == 0) ? acc0 : (q == 1) ? acc1 : (q == 2) ? acc2 : acc3;
        int ao  = (q & 2) ? (284 - ap) : ap;
        int det = (q & 1) ? (182 - j) : j;
        // ap==142 self-pairs: q2/q3 rewrite q0/q1's outputs with fp-equal
        // values — benign.
        out[img * RAYS + ao * ND + det] = v * (DT_F / 12.0f);
    }
}

extern "C" void kernel_launch(void* const* d_in, const int* in_sizes, int n_in,
                              void* d_out, int out_size, void* d_ws, size_t ws_size,
                              hipStream_t stream) {
    const float* x = (const float*)d_in[0];
    float* out = (float*)d_out;
    const int B = in_sizes[0] / (NI * NI);   // 8
    dim3 grid(B * 64);
    radon_fwd<<<grid, TPB, 0, stream>>>(x, out);
}